// Round 3
// baseline (653.157 us; speedup 1.0000x reference)
//
#include <hip/hip_runtime.h>
#include <hip/hip_bf16.h>

// ---------------------------------------------------------------------------
// Spatial_AttLayer on MI355X (gfx950), bf16 MFMA.
//
// Round-3: persistent-WG kernel. All three prior versions (~270-320 us) were
// latency-bound: every WG re-read Wo from L2 inside GEMM3 (16 serial latency
// steps, VGPR=48 -> no load-ahead) and paid cold staging latency. Fix:
//   * grid = 256 WGs (1 per CU), each loops over 16 t-blocks (2 t's each)
//   * Wo fragments pinned in VGPRs (wo[2][16] = 128 regs), loaded once;
//     Wv/attn fragments + biases hoisted too -> GEMM1/2/3 are pure LDS+MFMA
//   * next block's feature loads issued at top of iteration (sched_barrier
//     pins them), staged to the other Fl buffer at the bottom -> HBM latency
//     hidden under compute
//   * LDS 143,360 B: Fl double-buffer separate from Zl; pads zeroed once
//   * nontemporal out stores (write-once data; keep L3 for feature)
// Chain per block:  Vm = Wv@F + bv ; Z = Vm@[A_0|..|A_7] ; Out = Wo@Z + bo + F
// ---------------------------------------------------------------------------

typedef __attribute__((ext_vector_type(8))) short short8;
typedef __attribute__((ext_vector_type(4))) short short4v;
typedef __attribute__((ext_vector_type(4))) float f4v;

static __device__ __forceinline__ unsigned short f2bf(float f) {
  union { float f; unsigned u; } v; v.f = f;
  unsigned r = v.u + 0x7fffu + ((v.u >> 16) & 1u);   // RNE
  return (unsigned short)(r >> 16);
}
static __device__ __forceinline__ float bf2f(unsigned short h) {
  union { unsigned u; float f; } v; v.u = ((unsigned)h) << 16;
  return v.f;
}

// ws layout (unsigned short units unless noted):
//   WvP   [64][256]        bf16                               16384 elems
//   WoP   [256][512]       bf16 (plain cast, native order)   131072 elems
//   attnP [8][32][40]      bf16 (B-layout [vp][u], zero-pad)  10240 elems
//   qkP   [2][8][64][25]   f32 (q then k)                     25600 floats

// ---------------------------------------------------------------------------
// Kernel 1a: q/k 1x1 conv (one dot per thread) + weight conversions.
__global__ void k_qk_conv(const float* __restrict__ tf,
                          const float* __restrict__ Wq, const float* __restrict__ bq,
                          const float* __restrict__ Wk, const float* __restrict__ bk,
                          const float* __restrict__ Wv, const float* __restrict__ Wo,
                          unsigned short* __restrict__ WvP,
                          unsigned short* __restrict__ WoP,
                          float* __restrict__ qkP)
{
  __shared__ float tfl[12800];
  const int b = blockIdx.x, tid = threadIdx.x;
  if (b < 100) {
    for (int i = tid; i < 12800; i += 256) tfl[i] = tf[i];
    __syncthreads();
    int idx = b * 256 + tid;                    // 0..25599
    int isK = idx >= 12800;
    int j = isK ? idx - 12800 : idx;
    int g = j / 25, u = j - 25 * g;             // g: 0..511
    const float* wrow = (isK ? Wk : Wq) + g * 512;
    float s = (isK ? bk : bq)[g];
    for (int i = 0; i < 512; ++i) s += wrow[i] * tfl[i * 25 + u];
    qkP[idx] = s;
  } else {
    int cb = b - 100;                           // 0..63
    for (int i = cb * 256 + tid; i < 16384; i += 64 * 256) {
      WvP[i] = f2bf(Wv[i]);                     // [c][k] row-major, same as Wv
    }
    for (int i = cb * 256 + tid; i < 131072; i += 64 * 256) {
      WoP[i] = f2bf(Wo[i]);                     // native [o][h*64+c] order
    }
  }
}

// ---------------------------------------------------------------------------
// Kernel 1b: energy + softmax per head -> attnP (zero-padded B-layout).
__global__ void k_attn(const float* __restrict__ qkP,
                       unsigned short* __restrict__ attnP)
{
  __shared__ float ql[1600], kl[1600], attl[625];
  const int h = blockIdx.x, tid = threadIdx.x;
  for (int i = tid; i < 1600; i += 256) {
    ql[i] = qkP[h * 1600 + i];
    kl[i] = qkP[12800 + h * 1600 + i];
  }
  __syncthreads();
  if (tid < 25) {
    int u = tid;
    float e[25];
    float mx = -1e30f;
    #pragma unroll
    for (int v = 0; v < 25; ++v) {
      float s = 0.f;
      #pragma unroll
      for (int r = 0; r < 64; ++r) s += ql[r * 25 + u] * kl[r * 25 + v];
      s *= 0.125f;                              // 1/sqrt(64)
      e[v] = s;
      mx = fmaxf(mx, s);
    }
    float den = 0.f;
    #pragma unroll
    for (int v = 0; v < 25; ++v) { e[v] = __expf(e[v] - mx); den += e[v]; }
    float inv = 1.f / den;
    #pragma unroll
    for (int v = 0; v < 25; ++v) attl[u * 25 + v] = e[v] * inv;
  }
  __syncthreads();
  // attnP[h][vp][u] = attn[u][vp]; zero where u>=25 or vp>=25
  for (int i = tid; i < 1280; i += 256) {
    int vp = i / 40, u = i - 40 * vp;
    attnP[h * 1280 + i] =
        (vp < 25 && u < 25) ? f2bf(attl[u * 25 + vp]) : (unsigned short)0;
  }
}

// ---------------------------------------------------------------------------
// Main fused persistent kernel. 512 threads (8 waves), 1 WG/CU.
// LDS: FlA [64][264] @0 | FlB [64][264] @33792 | Vl [64][72] @67584
//      | Zl [64][520] @76800   -> total 143360 B
__launch_bounds__(512, 2)
__global__ void k_main(const float* __restrict__ feature,
                       const float* __restrict__ bv,
                       const float* __restrict__ bo,
                       const unsigned short* __restrict__ WvP,
                       const unsigned short* __restrict__ WoP,
                       const unsigned short* __restrict__ attnP,
                       float* __restrict__ out)
{
  extern __shared__ char smem[];
  unsigned short* FlA = (unsigned short*)smem;             // [64][264]
  unsigned short* FlB = (unsigned short*)(smem + 33792);   // [64][264]
  unsigned short* Vl  = (unsigned short*)(smem + 67584);   // [64][72]
  unsigned short* Zl  = (unsigned short*)(smem + 76800);   // [64][520]

  const int tid  = threadIdx.x;
  const int wave = tid >> 6;
  const int lane = tid & 63;
  const int quad = lane >> 4;
  const int l16  = lane & 15;
  const int wg    = blockIdx.x;
  const int n     = wg >> 5;                   // 0..7
  const int chunk = wg & 31;                   // t0 = chunk*32 + it*2

  const int c = tid >> 1, p = tid & 1;
  const size_t rowbase = ((size_t)(n * 256 + c) * 1024) * 25;   // floats

  // ---- persistent fragments (loaded once) ----
  short8 wo[2][16];                            // GEMM3 A: rows wave*32..+32
  #pragma unroll
  for (int mi = 0; mi < 2; ++mi)
    #pragma unroll
    for (int ks = 0; ks < 16; ++ks)
      wo[mi][ks] = *reinterpret_cast<const short8*>(
          WoP + (wave * 32 + mi * 16 + l16) * 512 + ks * 32 + quad * 8);

  const int mt1 = wave & 3, nh1 = wave >> 2;   // GEMM1 wave grid
  short8 wa[8];
  #pragma unroll
  for (int ks = 0; ks < 8; ++ks)
    wa[ks] = *reinterpret_cast<const short8*>(
        WvP + (mt1 * 16 + l16) * 256 + ks * 32 + quad * 8);

  const int t2 = wave >> 2, q2 = wave & 3;     // GEMM2 wave grid
  short8 ab[4];
  #pragma unroll
  for (int nj = 0; nj < 4; ++nj) {
    int h = 2 * q2 + (nj >> 1), vph = nj & 1;
    ab[nj] = *reinterpret_cast<const short8*>(
        attnP + h * 1280 + (vph * 16 + l16) * 40 + quad * 8);
  }

  float bo4[2][4];
  #pragma unroll
  for (int mi = 0; mi < 2; ++mi)
    #pragma unroll
    for (int r = 0; r < 4; ++r) bo4[mi][r] = bo[wave * 32 + mi * 16 + quad * 4 + r];
  float bvv[4];
  #pragma unroll
  for (int r = 0; r < 4; ++r) bvv[r] = bv[mt1 * 16 + quad * 4 + r];

  // ---- zero pad cols (vp 25..31) of BOTH F buffers, once ----
  {
    short8 z = {0, 0, 0, 0, 0, 0, 0, 0};
    for (int i = tid; i < 924; i += 512) {     // 28 pad cols x 33 short8
      int pc = i / 33, off = i - 33 * pc;      // pc 0..27
      unsigned short* F = (pc < 14) ? FlA : FlB;
      int r = (pc < 14) ? pc : pc - 14;
      int t = r / 7, vp = 25 + (r - 7 * t);
      *reinterpret_cast<short8*>(&F[(t * 32 + vp) * 264 + off * 8]) = z;
    }
  }

  // ---- prologue: load + stage block 0 into FlA ----
  float2 fn[13];
  {
    const float2* s2 = reinterpret_cast<const float2*>(
        feature + rowbase + (size_t)(chunk * 32) * 25);
    #pragma unroll
    for (int j = 0; j < 13; ++j) { int i = p + 2 * j; if (i < 25) fn[j] = s2[i]; }
  }
  #pragma unroll
  for (int j = 0; j < 13; ++j) {
    int i = p + 2 * j;
    if (i < 25) {
      int j0 = 2 * i;
      { int jj = j0;     int t = (jj >= 25); int vp = jj - 25 * t; FlA[(t*32+vp)*264 + c] = f2bf(fn[j].x); }
      { int jj = j0 + 1; int t = (jj >= 25); int vp = jj - 25 * t; FlA[(t*32+vp)*264 + c] = f2bf(fn[j].y); }
    }
  }
  __syncthreads();

  // ---- persistent loop over 16 t-blocks ----
  #pragma unroll 1
  for (int it = 0; it < 16; ++it) {
    unsigned short* Fc  = (it & 1) ? FlB : FlA;
    unsigned short* Fnx = (it & 1) ? FlA : FlB;
    const int t0 = chunk * 32 + it * 2;

    // (A) issue next block's feature loads; pin them above the compute
    if (it < 15) {
      const float2* s2 = reinterpret_cast<const float2*>(
          feature + rowbase + (size_t)(t0 + 2) * 25);
      #pragma unroll
      for (int j = 0; j < 13; ++j) { int i = p + 2 * j; if (i < 25) fn[j] = s2[i]; }
      __builtin_amdgcn_sched_barrier(0);       // don't sink loads into (F)
    }

    // (B) acc init: bias + residual from Fc
    f4v acc[2][4];
    #pragma unroll
    for (int mi = 0; mi < 2; ++mi) {
      const int o0 = wave * 32 + mi * 16 + quad * 4;
      #pragma unroll
      for (int ni = 0; ni < 4; ++ni) {
        short4v fr = *reinterpret_cast<const short4v*>(&Fc[(ni * 16 + l16) * 264 + o0]);
        #pragma unroll
        for (int r = 0; r < 4; ++r)
          acc[mi][ni][r] = bo4[mi][r] + bf2f((unsigned short)fr[r]);
      }
    }

    // (C) GEMM1: Vm = Wv@F + bv -> Vl
    {
      f4v accv[2];
      #pragma unroll
      for (int ni = 0; ni < 2; ++ni)
        #pragma unroll
        for (int r = 0; r < 4; ++r) accv[ni][r] = bvv[r];
      #pragma unroll
      for (int ks = 0; ks < 8; ++ks) {
        #pragma unroll
        for (int ni = 0; ni < 2; ++ni) {
          int colb = (2 * nh1 + ni) * 16 + l16;
          short8 b = *reinterpret_cast<const short8*>(&Fc[colb * 264 + ks * 32 + quad * 8]);
          accv[ni] = __builtin_amdgcn_mfma_f32_16x16x32_bf16(wa[ks], b, accv[ni], 0, 0, 0);
        }
      }
      #pragma unroll
      for (int ni = 0; ni < 2; ++ni) {
        int colb = (2 * nh1 + ni) * 16 + l16;
        #pragma unroll
        for (int r = 0; r < 4; ++r) {
          int cc = mt1 * 16 + quad * 4 + r;
          Vl[cc * 72 + colb] = f2bf(accv[ni][r]);
        }
      }
    }
    __syncthreads();                           // Vl ready; Fc consumed

    // (D) GEMM2: Z = Vm @ [A_0|..|A_7] -> Zl
    #pragma unroll
    for (int mi = 0; mi < 4; ++mi) {
      short8 a = *reinterpret_cast<const short8*>(
          &Vl[(mi * 16 + l16) * 72 + t2 * 32 + quad * 8]);
      #pragma unroll
      for (int nj = 0; nj < 4; ++nj) {
        f4v z = {0.f, 0.f, 0.f, 0.f};
        f4v az = __builtin_amdgcn_mfma_f32_16x16x32_bf16(a, ab[nj], z, 0, 0, 0);
        int h = 2 * q2 + (nj >> 1), vph = nj & 1;
        int col = t2 * 32 + vph * 16 + l16;
        int k0 = h * 64 + mi * 16 + quad * 4;
        short4v zz;
        #pragma unroll
        for (int r = 0; r < 4; ++r) zz[r] = (short)f2bf(az[r]);
        *reinterpret_cast<short4v*>(&Zl[col * 520 + k0]) = zz;
      }
    }
    __syncthreads();                           // Zl ready

    // (E) GEMM3: acc += Wo@Z (pure LDS+reg) + nontemporal stores
    #pragma unroll
    for (int ks = 0; ks < 16; ++ks) {
      short8 bfr[4];
      #pragma unroll
      for (int ni = 0; ni < 4; ++ni)
        bfr[ni] = *reinterpret_cast<const short8*>(
            &Zl[(ni * 16 + l16) * 520 + ks * 32 + quad * 8]);
      #pragma unroll
      for (int mi = 0; mi < 2; ++mi)
        #pragma unroll
        for (int ni = 0; ni < 4; ++ni)
          acc[mi][ni] =
              __builtin_amdgcn_mfma_f32_16x16x32_bf16(wo[mi][ks], bfr[ni], acc[mi][ni], 0, 0, 0);
    }

    #pragma unroll
    for (int ni = 0; ni < 4; ++ni) {
      int colb = ni * 16 + l16;
      int t = colb >> 5, vp = colb & 31;
      if (vp < 25) {
        #pragma unroll
        for (int mi = 0; mi < 2; ++mi)
          #pragma unroll
          for (int r = 0; r < 4; ++r) {
            int o = wave * 32 + mi * 16 + quad * 4 + r;
            __builtin_nontemporal_store(
                acc[mi][ni][r],
                &out[((size_t)(n * 256 + o) * 1024 + (t0 + t)) * 25 + vp]);
          }
      }
    }

    // (F) stage next block into the other F buffer
    if (it < 15) {
      #pragma unroll
      for (int j = 0; j < 13; ++j) {
        int i = p + 2 * j;
        if (i < 25) {
          int j0 = 2 * i;
          { int jj = j0;     int t = (jj >= 25); int vp = jj - 25 * t; Fnx[(t*32+vp)*264 + c] = f2bf(fn[j].x); }
          { int jj = j0 + 1; int t = (jj >= 25); int vp = jj - 25 * t; Fnx[(t*32+vp)*264 + c] = f2bf(fn[j].y); }
        }
      }
    }
    __syncthreads();                           // Fnx ready; Zl consumed
  }
}

// ---------------------------------------------------------------------------
extern "C" void kernel_launch(void* const* d_in, const int* in_sizes, int n_in,
                              void* d_out, int out_size, void* d_ws, size_t ws_size,
                              hipStream_t stream)
{
  const float* feature = (const float*)d_in[0];
  const float* tf      = (const float*)d_in[1];
  const float* Wq      = (const float*)d_in[2];
  const float* bq      = (const float*)d_in[3];
  const float* Wk      = (const float*)d_in[4];
  const float* bk      = (const float*)d_in[5];
  const float* Wv      = (const float*)d_in[6];
  const float* bv      = (const float*)d_in[7];
  const float* Wo      = (const float*)d_in[8];
  const float* bo      = (const float*)d_in[9];
  float* out = (float*)d_out;

  unsigned short* WvP   = (unsigned short*)d_ws;        // 16384
  unsigned short* WoP   = WvP + 16384;                  // 131072
  unsigned short* attnP = WoP + 131072;                 // 10240
  float* qkP = (float*)(attnP + 10240);                 // 25600 floats

  hipLaunchKernelGGL(k_qk_conv, dim3(164), dim3(256), 0, stream,
                     tf, Wq, bq, Wk, bk, Wv, Wo, WvP, WoP, qkP);
  hipLaunchKernelGGL(k_attn, dim3(8), dim3(256), 0, stream, qkP, attnP);

  hipFuncSetAttribute(reinterpret_cast<const void*>(&k_main),
                      hipFuncAttributeMaxDynamicSharedMemorySize, 143360);
  hipLaunchKernelGGL(k_main, dim3(256), dim3(512), 143360, stream,
                     feature, bv, bo, WvP, WoP, attnP, out);
}

// Round 4
// 556.217 us; speedup vs baseline: 1.1743x; 1.1743x over previous
//
#include <hip/hip_runtime.h>
#include <hip/hip_bf16.h>

// ---------------------------------------------------------------------------
// Spatial_AttLayer on MI355X (gfx950), bf16 MFMA.
//
// Round-4: round-3 persistent design with its two defects fixed:
//   * __launch_bounds__(512) -> VGPR cap 256 (round 3's (512,2) capped at 128
//     and spilled the 128-reg wo[] array to scratch: +95MB FETCH, +serial
//     scratch reloads). Register peak re-planned to ~240: fn committed right
//     after GEMM1 (frees 26 regs), acc-init moved after GEMM1.
//   * plain stores (round 3's nontemporal stores RMW'd partial 64B lines:
//     WRITE_SIZE 226->431 MB).
//   * 2 barriers/iteration (end-of-iter barrier was redundant).
// Design: 256 persistent WGs (1/CU), 16 t-blocks each. Wo pinned in VGPRs
// (wo[2][16]), Wv/attn fragments + biases hoisted; GEMM1/2/3 pure LDS+MFMA;
// next block's feature loads issued at top of iteration, committed after
// GEMM1 (global latency hidden under compute).
// Chain per block: Vm = Wv@F + bv ; Z = Vm@[A_0|..|A_7] ; Out = Wo@Z + bo + F
// ---------------------------------------------------------------------------

typedef __attribute__((ext_vector_type(8))) short short8;
typedef __attribute__((ext_vector_type(4))) short short4v;
typedef __attribute__((ext_vector_type(4))) float f4v;

static __device__ __forceinline__ unsigned short f2bf(float f) {
  union { float f; unsigned u; } v; v.f = f;
  unsigned r = v.u + 0x7fffu + ((v.u >> 16) & 1u);   // RNE
  return (unsigned short)(r >> 16);
}
static __device__ __forceinline__ float bf2f(unsigned short h) {
  union { unsigned u; float f; } v; v.u = ((unsigned)h) << 16;
  return v.f;
}

// ws layout (unsigned short units unless noted):
//   WvP   [64][256]        bf16                               16384 elems
//   WoP   [256][512]       bf16 (plain cast, native order)   131072 elems
//   attnP [8][32][40]      bf16 (B-layout [vp][u], zero-pad)  10240 elems
//   qkP   [2][8][64][25]   f32 (q then k)                     25600 floats

// ---------------------------------------------------------------------------
// Kernel 1a: q/k 1x1 conv (one dot per thread) + weight conversions.
__global__ void k_qk_conv(const float* __restrict__ tf,
                          const float* __restrict__ Wq, const float* __restrict__ bq,
                          const float* __restrict__ Wk, const float* __restrict__ bk,
                          const float* __restrict__ Wv, const float* __restrict__ Wo,
                          unsigned short* __restrict__ WvP,
                          unsigned short* __restrict__ WoP,
                          float* __restrict__ qkP)
{
  __shared__ float tfl[12800];
  const int b = blockIdx.x, tid = threadIdx.x;
  if (b < 100) {
    for (int i = tid; i < 12800; i += 256) tfl[i] = tf[i];
    __syncthreads();
    int idx = b * 256 + tid;                    // 0..25599
    int isK = idx >= 12800;
    int j = isK ? idx - 12800 : idx;
    int g = j / 25, u = j - 25 * g;             // g: 0..511
    const float* wrow = (isK ? Wk : Wq) + g * 512;
    float s = (isK ? bk : bq)[g];
    for (int i = 0; i < 512; ++i) s += wrow[i] * tfl[i * 25 + u];
    qkP[idx] = s;
  } else {
    int cb = b - 100;                           // 0..63
    for (int i = cb * 256 + tid; i < 16384; i += 64 * 256) {
      WvP[i] = f2bf(Wv[i]);                     // [c][k] row-major, same as Wv
    }
    for (int i = cb * 256 + tid; i < 131072; i += 64 * 256) {
      WoP[i] = f2bf(Wo[i]);                     // native [o][h*64+c] order
    }
  }
}

// ---------------------------------------------------------------------------
// Kernel 1b: energy + softmax per head -> attnP (zero-padded B-layout).
__global__ void k_attn(const float* __restrict__ qkP,
                       unsigned short* __restrict__ attnP)
{
  __shared__ float ql[1600], kl[1600], attl[625];
  const int h = blockIdx.x, tid = threadIdx.x;
  for (int i = tid; i < 1600; i += 256) {
    ql[i] = qkP[h * 1600 + i];
    kl[i] = qkP[12800 + h * 1600 + i];
  }
  __syncthreads();
  if (tid < 25) {
    int u = tid;
    float e[25];
    float mx = -1e30f;
    #pragma unroll
    for (int v = 0; v < 25; ++v) {
      float s = 0.f;
      #pragma unroll
      for (int r = 0; r < 64; ++r) s += ql[r * 25 + u] * kl[r * 25 + v];
      s *= 0.125f;                              // 1/sqrt(64)
      e[v] = s;
      mx = fmaxf(mx, s);
    }
    float den = 0.f;
    #pragma unroll
    for (int v = 0; v < 25; ++v) { e[v] = __expf(e[v] - mx); den += e[v]; }
    float inv = 1.f / den;
    #pragma unroll
    for (int v = 0; v < 25; ++v) attl[u * 25 + v] = e[v] * inv;
  }
  __syncthreads();
  // attnP[h][vp][u] = attn[u][vp]; zero where u>=25 or vp>=25
  for (int i = tid; i < 1280; i += 256) {
    int vp = i / 40, u = i - 40 * vp;
    attnP[h * 1280 + i] =
        (vp < 25 && u < 25) ? f2bf(attl[u * 25 + vp]) : (unsigned short)0;
  }
}

// ---------------------------------------------------------------------------
// Main fused persistent kernel. 512 threads (8 waves), 1 WG/CU (VGPR-bound).
// LDS: FlA [64][264] @0 | FlB [64][264] @33792 | Vl [64][72] @67584
//      | Zl [64][520] @76800   -> total 143360 B
__launch_bounds__(512)
__global__ void k_main(const float* __restrict__ feature,
                       const float* __restrict__ bv,
                       const float* __restrict__ bo,
                       const unsigned short* __restrict__ WvP,
                       const unsigned short* __restrict__ WoP,
                       const unsigned short* __restrict__ attnP,
                       float* __restrict__ out)
{
  extern __shared__ char smem[];
  unsigned short* FlA = (unsigned short*)smem;             // [64][264]
  unsigned short* FlB = (unsigned short*)(smem + 33792);   // [64][264]
  unsigned short* Vl  = (unsigned short*)(smem + 67584);   // [64][72]
  unsigned short* Zl  = (unsigned short*)(smem + 76800);   // [64][520]

  const int tid  = threadIdx.x;
  const int wave = tid >> 6;
  const int lane = tid & 63;
  const int quad = lane >> 4;
  const int l16  = lane & 15;
  const int wg    = blockIdx.x;
  const int n     = wg & 7;                    // one batch image per XCD
  const int chunk = wg >> 3;                   // 0..31; t0 = chunk*32 + it*2

  const int c = tid >> 1, p = tid & 1;
  const size_t rowbase = ((size_t)(n * 256 + c) * 1024) * 25;   // floats

  // ---- persistent fragments (loaded once; register budget ~160) ----
  short8 wo[2][16];                            // GEMM3 A: rows wave*32..+32
  #pragma unroll
  for (int mi = 0; mi < 2; ++mi)
    #pragma unroll
    for (int ks = 0; ks < 16; ++ks)
      wo[mi][ks] = *reinterpret_cast<const short8*>(
          WoP + (wave * 32 + mi * 16 + l16) * 512 + ks * 32 + quad * 8);

  const int mt1 = wave & 3, nh1 = wave >> 2;   // GEMM1 wave grid
  short8 wa[8];
  #pragma unroll
  for (int ks = 0; ks < 8; ++ks)
    wa[ks] = *reinterpret_cast<const short8*>(
        WvP + (mt1 * 16 + l16) * 256 + ks * 32 + quad * 8);

  const int t2 = wave >> 2, q2 = wave & 3;     // GEMM2 wave grid
  short8 ab[4];
  #pragma unroll
  for (int nj = 0; nj < 4; ++nj) {
    int h = 2 * q2 + (nj >> 1), vph = nj & 1;
    ab[nj] = *reinterpret_cast<const short8*>(
        attnP + h * 1280 + (vph * 16 + l16) * 40 + quad * 8);
  }

  float bo4[2][4];
  #pragma unroll
  for (int mi = 0; mi < 2; ++mi)
    #pragma unroll
    for (int r = 0; r < 4; ++r) bo4[mi][r] = bo[wave * 32 + mi * 16 + quad * 4 + r];
  float bvv[4];
  #pragma unroll
  for (int r = 0; r < 4; ++r) bvv[r] = bv[mt1 * 16 + quad * 4 + r];

  // ---- zero pad cols (vp 25..31) of BOTH F buffers, once ----
  {
    short8 z = {0, 0, 0, 0, 0, 0, 0, 0};
    for (int i = tid; i < 924; i += 512) {     // 28 pad cols x 33 short8
      int pc = i / 33, off = i - 33 * pc;      // pc 0..27
      unsigned short* F = (pc < 14) ? FlA : FlB;
      int r = (pc < 14) ? pc : pc - 14;
      int t = r / 7, vp = 25 + (r - 7 * t);
      *reinterpret_cast<short8*>(&F[(t * 32 + vp) * 264 + off * 8]) = z;
    }
  }

  // ---- prologue: load + stage block 0 into FlA ----
  {
    float2 f0[13];
    const float2* s2 = reinterpret_cast<const float2*>(
        feature + rowbase + (size_t)(chunk * 32) * 25);
    #pragma unroll
    for (int j = 0; j < 13; ++j) { int i = p + 2 * j; if (i < 25) f0[j] = s2[i]; }
    #pragma unroll
    for (int j = 0; j < 13; ++j) {
      int i = p + 2 * j;
      if (i < 25) {
        int j0 = 2 * i;
        { int jj = j0;     int t = (jj >= 25); int vp = jj - 25 * t; FlA[(t*32+vp)*264 + c] = f2bf(f0[j].x); }
        { int jj = j0 + 1; int t = (jj >= 25); int vp = jj - 25 * t; FlA[(t*32+vp)*264 + c] = f2bf(f0[j].y); }
      }
    }
  }
  __syncthreads();

  // ---- persistent loop over 16 t-blocks (2 barriers per iteration) ----
  #pragma unroll 1
  for (int it = 0; it < 16; ++it) {
    unsigned short* Fc  = (it & 1) ? FlB : FlA;
    unsigned short* Fnx = (it & 1) ? FlA : FlB;
    const int t0 = chunk * 32 + it * 2;

    // (A) issue next block's feature loads; pin above compute
    float2 fn[13];
    if (it < 15) {
      const float2* s2 = reinterpret_cast<const float2*>(
          feature + rowbase + (size_t)(t0 + 2) * 25);
      #pragma unroll
      for (int j = 0; j < 13; ++j) { int i = p + 2 * j; if (i < 25) fn[j] = s2[i]; }
      __builtin_amdgcn_sched_barrier(0);       // don't sink loads below
    }

    // (B) GEMM1: Vm = Wv@F + bv -> Vl
    {
      f4v accv[2];
      #pragma unroll
      for (int ni = 0; ni < 2; ++ni)
        #pragma unroll
        for (int r = 0; r < 4; ++r) accv[ni][r] = bvv[r];
      #pragma unroll
      for (int ks = 0; ks < 8; ++ks) {
        #pragma unroll
        for (int ni = 0; ni < 2; ++ni) {
          int colb = (2 * nh1 + ni) * 16 + l16;
          short8 b = *reinterpret_cast<const short8*>(&Fc[colb * 264 + ks * 32 + quad * 8]);
          accv[ni] = __builtin_amdgcn_mfma_f32_16x16x32_bf16(wa[ks], b, accv[ni], 0, 0, 0);
        }
      }
      #pragma unroll
      for (int ni = 0; ni < 2; ++ni) {
        int colb = (2 * nh1 + ni) * 16 + l16;
        #pragma unroll
        for (int r = 0; r < 4; ++r) {
          int cc = mt1 * 16 + quad * 4 + r;
          Vl[cc * 72 + colb] = f2bf(accv[ni][r]);
        }
      }
    }

    // (C) commit next F block (frees fn registers before acc goes live).
    //     Fnx's prior readers finished before the barriers of iteration it-1.
    if (it < 15) {
      #pragma unroll
      for (int j = 0; j < 13; ++j) {
        int i = p + 2 * j;
        if (i < 25) {
          int j0 = 2 * i;
          { int jj = j0;     int t = (jj >= 25); int vp = jj - 25 * t; Fnx[(t*32+vp)*264 + c] = f2bf(fn[j].x); }
          { int jj = j0 + 1; int t = (jj >= 25); int vp = jj - 25 * t; Fnx[(t*32+vp)*264 + c] = f2bf(fn[j].y); }
        }
      }
    }

    // (D) acc init: bias + residual from Fc (Fc still alive until barrier 1)
    f4v acc[2][4];
    #pragma unroll
    for (int mi = 0; mi < 2; ++mi) {
      const int o0 = wave * 32 + mi * 16 + quad * 4;
      #pragma unroll
      for (int ni = 0; ni < 4; ++ni) {
        short4v fr = *reinterpret_cast<const short4v*>(&Fc[(ni * 16 + l16) * 264 + o0]);
        #pragma unroll
        for (int r = 0; r < 4; ++r)
          acc[mi][ni][r] = bo4[mi][r] + bf2f((unsigned short)fr[r]);
      }
    }
    __syncthreads();                           // barrier 1: Vl ready

    // (E) GEMM2: Z = Vm @ [A_0|..|A_7] -> Zl
    #pragma unroll
    for (int mi = 0; mi < 4; ++mi) {
      short8 a = *reinterpret_cast<const short8*>(
          &Vl[(mi * 16 + l16) * 72 + t2 * 32 + quad * 8]);
      #pragma unroll
      for (int nj = 0; nj < 4; ++nj) {
        f4v z = {0.f, 0.f, 0.f, 0.f};
        f4v az = __builtin_amdgcn_mfma_f32_16x16x32_bf16(a, ab[nj], z, 0, 0, 0);
        int h = 2 * q2 + (nj >> 1), vph = nj & 1;
        int col = t2 * 32 + vph * 16 + l16;
        int k0 = h * 64 + mi * 16 + quad * 4;
        short4v zz;
        #pragma unroll
        for (int r = 0; r < 4; ++r) zz[r] = (short)f2bf(az[r]);
        *reinterpret_cast<short4v*>(&Zl[col * 520 + k0]) = zz;
      }
    }
    __syncthreads();                           // barrier 2: Zl ready

    // (F) GEMM3: acc += Wo@Z (pure reg+LDS) + plain stores
    #pragma unroll
    for (int ks = 0; ks < 16; ++ks) {
      short8 bfr[4];
      #pragma unroll
      for (int ni = 0; ni < 4; ++ni)
        bfr[ni] = *reinterpret_cast<const short8*>(
            &Zl[(ni * 16 + l16) * 520 + ks * 32 + quad * 8]);
      #pragma unroll
      for (int mi = 0; mi < 2; ++mi)
        #pragma unroll
        for (int ni = 0; ni < 4; ++ni)
          acc[mi][ni] =
              __builtin_amdgcn_mfma_f32_16x16x32_bf16(wo[mi][ks], bfr[ni], acc[mi][ni], 0, 0, 0);
    }

    #pragma unroll
    for (int ni = 0; ni < 4; ++ni) {
      int colb = ni * 16 + l16;
      int t = colb >> 5, vp = colb & 31;
      if (vp < 25) {
        #pragma unroll
        for (int mi = 0; mi < 2; ++mi)
          #pragma unroll
          for (int r = 0; r < 4; ++r) {
            int o = wave * 32 + mi * 16 + quad * 4 + r;
            out[((size_t)(n * 256 + o) * 1024 + (t0 + t)) * 25 + vp] = acc[mi][ni][r];
          }
      }
    }
    // no barrier here: barrier 1 of the next iteration orders GEMM3's
    // Zl reads against the next GEMM2's Zl writes.
  }
}

// ---------------------------------------------------------------------------
extern "C" void kernel_launch(void* const* d_in, const int* in_sizes, int n_in,
                              void* d_out, int out_size, void* d_ws, size_t ws_size,
                              hipStream_t stream)
{
  const float* feature = (const float*)d_in[0];
  const float* tf      = (const float*)d_in[1];
  const float* Wq      = (const float*)d_in[2];
  const float* bq      = (const float*)d_in[3];
  const float* Wk      = (const float*)d_in[4];
  const float* bk      = (const float*)d_in[5];
  const float* Wv      = (const float*)d_in[6];
  const float* bv      = (const float*)d_in[7];
  const float* Wo      = (const float*)d_in[8];
  const float* bo      = (const float*)d_in[9];
  float* out = (float*)d_out;

  unsigned short* WvP   = (unsigned short*)d_ws;        // 16384
  unsigned short* WoP   = WvP + 16384;                  // 131072
  unsigned short* attnP = WoP + 131072;                 // 10240
  float* qkP = (float*)(attnP + 10240);                 // 25600 floats

  hipLaunchKernelGGL(k_qk_conv, dim3(164), dim3(256), 0, stream,
                     tf, Wq, bq, Wk, bk, Wv, Wo, WvP, WoP, qkP);
  hipLaunchKernelGGL(k_attn, dim3(8), dim3(256), 0, stream, qkP, attnP);

  hipFuncSetAttribute(reinterpret_cast<const void*>(&k_main),
                      hipFuncAttributeMaxDynamicSharedMemorySize, 143360);
  hipLaunchKernelGGL(k_main, dim3(256), dim3(512), 143360, stream,
                     feature, bv, bo, WvP, WoP, attnP, out);
}

// Round 5
// 530.691 us; speedup vs baseline: 1.2308x; 1.0481x over previous
//
#include <hip/hip_runtime.h>
#include <hip/hip_bf16.h>

// ---------------------------------------------------------------------------
// Spatial_AttLayer on MI355X (gfx950), bf16 MFMA.
//
// Round-5: same persistent design as round 4, ONE lever changed:
//   * __attribute__((amdgpu_waves_per_eu(2,2))): rounds 3 AND 4 both compiled
//     to VGPR_Count=128 (backend occupancy heuristic can't see the dynamic
//     143KB LDS that already forces 1 WG/CU = 2 waves/EU), so wo[2][16]
//     (128 VGPRs) was spilled/rematerialized every iteration -- the pinned-
//     weight experiment never actually ran. Pinning waves/EU to 2 allows the
//     allocator its full 256-reg budget. Planned peaks: GEMM1 ~240, GEMM3 ~242.
//   * GEMM3 B-fragments loaded per-ni (transient 4 regs instead of 16).
// Design recap: 256 persistent WGs (1/CU), 16 t-blocks each; Wo pinned in
// VGPRs; Wv/attn fragments + biases hoisted; GEMM1/2/3 pure LDS+MFMA; next
// block's feature loads issued at iteration top, committed after GEMM1.
// Chain per block: Vm = Wv@F + bv ; Z = Vm@[A_0|..|A_7] ; Out = Wo@Z + bo + F
// ---------------------------------------------------------------------------

typedef __attribute__((ext_vector_type(8))) short short8;
typedef __attribute__((ext_vector_type(4))) short short4v;
typedef __attribute__((ext_vector_type(4))) float f4v;

static __device__ __forceinline__ unsigned short f2bf(float f) {
  union { float f; unsigned u; } v; v.f = f;
  unsigned r = v.u + 0x7fffu + ((v.u >> 16) & 1u);   // RNE
  return (unsigned short)(r >> 16);
}
static __device__ __forceinline__ float bf2f(unsigned short h) {
  union { unsigned u; float f; } v; v.u = ((unsigned)h) << 16;
  return v.f;
}

// ws layout (unsigned short units unless noted):
//   WvP   [64][256]        bf16                               16384 elems
//   WoP   [256][512]       bf16 (plain cast, native order)   131072 elems
//   attnP [8][32][40]      bf16 (B-layout [vp][u], zero-pad)  10240 elems
//   qkP   [2][8][64][25]   f32 (q then k)                     25600 floats

// ---------------------------------------------------------------------------
// Kernel 1a: q/k 1x1 conv (one dot per thread) + weight conversions.
__global__ void k_qk_conv(const float* __restrict__ tf,
                          const float* __restrict__ Wq, const float* __restrict__ bq,
                          const float* __restrict__ Wk, const float* __restrict__ bk,
                          const float* __restrict__ Wv, const float* __restrict__ Wo,
                          unsigned short* __restrict__ WvP,
                          unsigned short* __restrict__ WoP,
                          float* __restrict__ qkP)
{
  __shared__ float tfl[12800];
  const int b = blockIdx.x, tid = threadIdx.x;
  if (b < 100) {
    for (int i = tid; i < 12800; i += 256) tfl[i] = tf[i];
    __syncthreads();
    int idx = b * 256 + tid;                    // 0..25599
    int isK = idx >= 12800;
    int j = isK ? idx - 12800 : idx;
    int g = j / 25, u = j - 25 * g;             // g: 0..511
    const float* wrow = (isK ? Wk : Wq) + g * 512;
    float s = (isK ? bk : bq)[g];
    for (int i = 0; i < 512; ++i) s += wrow[i] * tfl[i * 25 + u];
    qkP[idx] = s;
  } else {
    int cb = b - 100;                           // 0..63
    for (int i = cb * 256 + tid; i < 16384; i += 64 * 256) {
      WvP[i] = f2bf(Wv[i]);                     // [c][k] row-major, same as Wv
    }
    for (int i = cb * 256 + tid; i < 131072; i += 64 * 256) {
      WoP[i] = f2bf(Wo[i]);                     // native [o][h*64+c] order
    }
  }
}

// ---------------------------------------------------------------------------
// Kernel 1b: energy + softmax per head -> attnP (zero-padded B-layout).
__global__ void k_attn(const float* __restrict__ qkP,
                       unsigned short* __restrict__ attnP)
{
  __shared__ float ql[1600], kl[1600], attl[625];
  const int h = blockIdx.x, tid = threadIdx.x;
  for (int i = tid; i < 1600; i += 256) {
    ql[i] = qkP[h * 1600 + i];
    kl[i] = qkP[12800 + h * 1600 + i];
  }
  __syncthreads();
  if (tid < 25) {
    int u = tid;
    float e[25];
    float mx = -1e30f;
    #pragma unroll
    for (int v = 0; v < 25; ++v) {
      float s = 0.f;
      #pragma unroll
      for (int r = 0; r < 64; ++r) s += ql[r * 25 + u] * kl[r * 25 + v];
      s *= 0.125f;                              // 1/sqrt(64)
      e[v] = s;
      mx = fmaxf(mx, s);
    }
    float den = 0.f;
    #pragma unroll
    for (int v = 0; v < 25; ++v) { e[v] = __expf(e[v] - mx); den += e[v]; }
    float inv = 1.f / den;
    #pragma unroll
    for (int v = 0; v < 25; ++v) attl[u * 25 + v] = e[v] * inv;
  }
  __syncthreads();
  // attnP[h][vp][u] = attn[u][vp]; zero where u>=25 or vp>=25
  for (int i = tid; i < 1280; i += 256) {
    int vp = i / 40, u = i - 40 * vp;
    attnP[h * 1280 + i] =
        (vp < 25 && u < 25) ? f2bf(attl[u * 25 + vp]) : (unsigned short)0;
  }
}

// ---------------------------------------------------------------------------
// Main fused persistent kernel. 512 threads (8 waves), 1 WG/CU.
// LDS: FlA [64][264] @0 | FlB [64][264] @33792 | Vl [64][72] @67584
//      | Zl [64][520] @76800   -> total 143360 B
__launch_bounds__(512)
__attribute__((amdgpu_waves_per_eu(2, 2)))
__global__ void k_main(const float* __restrict__ feature,
                       const float* __restrict__ bv,
                       const float* __restrict__ bo,
                       const unsigned short* __restrict__ WvP,
                       const unsigned short* __restrict__ WoP,
                       const unsigned short* __restrict__ attnP,
                       float* __restrict__ out)
{
  extern __shared__ char smem[];
  unsigned short* FlA = (unsigned short*)smem;             // [64][264]
  unsigned short* FlB = (unsigned short*)(smem + 33792);   // [64][264]
  unsigned short* Vl  = (unsigned short*)(smem + 67584);   // [64][72]
  unsigned short* Zl  = (unsigned short*)(smem + 76800);   // [64][520]

  const int tid  = threadIdx.x;
  const int wave = tid >> 6;
  const int lane = tid & 63;
  const int quad = lane >> 4;
  const int l16  = lane & 15;
  const int wg    = blockIdx.x;
  const int n     = wg & 7;                    // one batch image per XCD
  const int chunk = wg >> 3;                   // 0..31; t0 = chunk*32 + it*2

  const int c = tid >> 1, p = tid & 1;
  const size_t rowbase = ((size_t)(n * 256 + c) * 1024) * 25;   // floats

  // ---- persistent fragments (loaded once; ~188 regs + addressing) ----
  short8 wo[2][16];                            // GEMM3 A: rows wave*32..+32
  #pragma unroll
  for (int mi = 0; mi < 2; ++mi)
    #pragma unroll
    for (int ks = 0; ks < 16; ++ks)
      wo[mi][ks] = *reinterpret_cast<const short8*>(
          WoP + (wave * 32 + mi * 16 + l16) * 512 + ks * 32 + quad * 8);

  const int mt1 = wave & 3, nh1 = wave >> 2;   // GEMM1 wave grid
  short8 wa[8];
  #pragma unroll
  for (int ks = 0; ks < 8; ++ks)
    wa[ks] = *reinterpret_cast<const short8*>(
        WvP + (mt1 * 16 + l16) * 256 + ks * 32 + quad * 8);

  const int t2 = wave >> 2, q2 = wave & 3;     // GEMM2 wave grid
  short8 ab[4];
  #pragma unroll
  for (int nj = 0; nj < 4; ++nj) {
    int h = 2 * q2 + (nj >> 1), vph = nj & 1;
    ab[nj] = *reinterpret_cast<const short8*>(
        attnP + h * 1280 + (vph * 16 + l16) * 40 + quad * 8);
  }

  float bo4[2][4];
  #pragma unroll
  for (int mi = 0; mi < 2; ++mi)
    #pragma unroll
    for (int r = 0; r < 4; ++r) bo4[mi][r] = bo[wave * 32 + mi * 16 + quad * 4 + r];
  float bvv[4];
  #pragma unroll
  for (int r = 0; r < 4; ++r) bvv[r] = bv[mt1 * 16 + quad * 4 + r];

  // ---- zero pad cols (vp 25..31) of BOTH F buffers, once ----
  {
    short8 z = {0, 0, 0, 0, 0, 0, 0, 0};
    for (int i = tid; i < 924; i += 512) {     // 28 pad cols x 33 short8
      int pc = i / 33, off = i - 33 * pc;      // pc 0..27
      unsigned short* F = (pc < 14) ? FlA : FlB;
      int r = (pc < 14) ? pc : pc - 14;
      int t = r / 7, vp = 25 + (r - 7 * t);
      *reinterpret_cast<short8*>(&F[(t * 32 + vp) * 264 + off * 8]) = z;
    }
  }

  // ---- prologue: load + stage block 0 into FlA ----
  {
    float2 f0[13];
    const float2* s2 = reinterpret_cast<const float2*>(
        feature + rowbase + (size_t)(chunk * 32) * 25);
    #pragma unroll
    for (int j = 0; j < 13; ++j) { int i = p + 2 * j; if (i < 25) f0[j] = s2[i]; }
    #pragma unroll
    for (int j = 0; j < 13; ++j) {
      int i = p + 2 * j;
      if (i < 25) {
        int j0 = 2 * i;
        { int jj = j0;     int t = (jj >= 25); int vp = jj - 25 * t; FlA[(t*32+vp)*264 + c] = f2bf(f0[j].x); }
        { int jj = j0 + 1; int t = (jj >= 25); int vp = jj - 25 * t; FlA[(t*32+vp)*264 + c] = f2bf(f0[j].y); }
      }
    }
  }
  __syncthreads();

  // ---- persistent loop over 16 t-blocks (2 barriers per iteration) ----
  #pragma unroll 1
  for (int it = 0; it < 16; ++it) {
    unsigned short* Fc  = (it & 1) ? FlB : FlA;
    unsigned short* Fnx = (it & 1) ? FlA : FlB;
    const int t0 = chunk * 32 + it * 2;

    // (A) issue next block's feature loads; pin above compute
    float2 fn[13];
    if (it < 15) {
      const float2* s2 = reinterpret_cast<const float2*>(
          feature + rowbase + (size_t)(t0 + 2) * 25);
      #pragma unroll
      for (int j = 0; j < 13; ++j) { int i = p + 2 * j; if (i < 25) fn[j] = s2[i]; }
      __builtin_amdgcn_sched_barrier(0);       // don't sink loads below
    }

    // (B) GEMM1: Vm = Wv@F + bv -> Vl
    {
      f4v accv[2];
      #pragma unroll
      for (int ni = 0; ni < 2; ++ni)
        #pragma unroll
        for (int r = 0; r < 4; ++r) accv[ni][r] = bvv[r];
      #pragma unroll
      for (int ks = 0; ks < 8; ++ks) {
        #pragma unroll
        for (int ni = 0; ni < 2; ++ni) {
          int colb = (2 * nh1 + ni) * 16 + l16;
          short8 b = *reinterpret_cast<const short8*>(&Fc[colb * 264 + ks * 32 + quad * 8]);
          accv[ni] = __builtin_amdgcn_mfma_f32_16x16x32_bf16(wa[ks], b, accv[ni], 0, 0, 0);
        }
      }
      #pragma unroll
      for (int ni = 0; ni < 2; ++ni) {
        int colb = (2 * nh1 + ni) * 16 + l16;
        #pragma unroll
        for (int r = 0; r < 4; ++r) {
          int cc = mt1 * 16 + quad * 4 + r;
          Vl[cc * 72 + colb] = f2bf(accv[ni][r]);
        }
      }
    }

    // (C) commit next F block (frees fn registers before acc goes live).
    if (it < 15) {
      #pragma unroll
      for (int j = 0; j < 13; ++j) {
        int i = p + 2 * j;
        if (i < 25) {
          int j0 = 2 * i;
          { int jj = j0;     int t = (jj >= 25); int vp = jj - 25 * t; Fnx[(t*32+vp)*264 + c] = f2bf(fn[j].x); }
          { int jj = j0 + 1; int t = (jj >= 25); int vp = jj - 25 * t; Fnx[(t*32+vp)*264 + c] = f2bf(fn[j].y); }
        }
      }
    }

    // (D) acc init: bias + residual from Fc (Fc alive until barrier 1)
    f4v acc[2][4];
    #pragma unroll
    for (int mi = 0; mi < 2; ++mi) {
      const int o0 = wave * 32 + mi * 16 + quad * 4;
      #pragma unroll
      for (int ni = 0; ni < 4; ++ni) {
        short4v fr = *reinterpret_cast<const short4v*>(&Fc[(ni * 16 + l16) * 264 + o0]);
        #pragma unroll
        for (int r = 0; r < 4; ++r)
          acc[mi][ni][r] = bo4[mi][r] + bf2f((unsigned short)fr[r]);
      }
    }
    __syncthreads();                           // barrier 1: Vl ready

    // (E) GEMM2: Z = Vm @ [A_0|..|A_7] -> Zl
    #pragma unroll
    for (int mi = 0; mi < 4; ++mi) {
      short8 a = *reinterpret_cast<const short8*>(
          &Vl[(mi * 16 + l16) * 72 + t2 * 32 + quad * 8]);
      #pragma unroll
      for (int nj = 0; nj < 4; ++nj) {
        f4v z = {0.f, 0.f, 0.f, 0.f};
        f4v az = __builtin_amdgcn_mfma_f32_16x16x32_bf16(a, ab[nj], z, 0, 0, 0);
        int h = 2 * q2 + (nj >> 1), vph = nj & 1;
        int col = t2 * 32 + vph * 16 + l16;
        int k0 = h * 64 + mi * 16 + quad * 4;
        short4v zz;
        #pragma unroll
        for (int r = 0; r < 4; ++r) zz[r] = (short)f2bf(az[r]);
        *reinterpret_cast<short4v*>(&Zl[col * 520 + k0]) = zz;
      }
    }
    __syncthreads();                           // barrier 2: Zl ready

    // (F) GEMM3: acc += Wo@Z (pure reg+LDS); B-fragments loaded per-ni
    #pragma unroll
    for (int ks = 0; ks < 16; ++ks) {
      #pragma unroll
      for (int ni = 0; ni < 4; ++ni) {
        short8 bfr = *reinterpret_cast<const short8*>(
            &Zl[(ni * 16 + l16) * 520 + ks * 32 + quad * 8]);
        #pragma unroll
        for (int mi = 0; mi < 2; ++mi)
          acc[mi][ni] =
              __builtin_amdgcn_mfma_f32_16x16x32_bf16(wo[mi][ks], bfr, acc[mi][ni], 0, 0, 0);
      }
    }

    #pragma unroll
    for (int ni = 0; ni < 4; ++ni) {
      int colb = ni * 16 + l16;
      int t = colb >> 5, vp = colb & 31;
      if (vp < 25) {
        #pragma unroll
        for (int mi = 0; mi < 2; ++mi)
          #pragma unroll
          for (int r = 0; r < 4; ++r) {
            int o = wave * 32 + mi * 16 + quad * 4 + r;
            out[((size_t)(n * 256 + o) * 1024 + (t0 + t)) * 25 + vp] = acc[mi][ni][r];
          }
      }
    }
    // no barrier here: barrier 1 of the next iteration orders GEMM3's
    // Zl reads against the next GEMM2's Zl writes.
  }
}

// ---------------------------------------------------------------------------
extern "C" void kernel_launch(void* const* d_in, const int* in_sizes, int n_in,
                              void* d_out, int out_size, void* d_ws, size_t ws_size,
                              hipStream_t stream)
{
  const float* feature = (const float*)d_in[0];
  const float* tf      = (const float*)d_in[1];
  const float* Wq      = (const float*)d_in[2];
  const float* bq      = (const float*)d_in[3];
  const float* Wk      = (const float*)d_in[4];
  const float* bk      = (const float*)d_in[5];
  const float* Wv      = (const float*)d_in[6];
  const float* bv      = (const float*)d_in[7];
  const float* Wo      = (const float*)d_in[8];
  const float* bo      = (const float*)d_in[9];
  float* out = (float*)d_out;

  unsigned short* WvP   = (unsigned short*)d_ws;        // 16384
  unsigned short* WoP   = WvP + 16384;                  // 131072
  unsigned short* attnP = WoP + 131072;                 // 10240
  float* qkP = (float*)(attnP + 10240);                 // 25600 floats

  hipLaunchKernelGGL(k_qk_conv, dim3(164), dim3(256), 0, stream,
                     tf, Wq, bq, Wk, bk, Wv, Wo, WvP, WoP, qkP);
  hipLaunchKernelGGL(k_attn, dim3(8), dim3(256), 0, stream, qkP, attnP);

  hipFuncSetAttribute(reinterpret_cast<const void*>(&k_main),
                      hipFuncAttributeMaxDynamicSharedMemorySize, 143360);
  hipLaunchKernelGGL(k_main, dim3(256), dim3(512), 143360, stream,
                     feature, bv, bo, WvP, WoP, attnP, out);
}